// Round 4
// baseline (512.495 us; speedup 1.0000x reference)
//
#include <hip/hip_runtime.h>
#include <hip/hip_bf16.h>

typedef __attribute__((ext_vector_type(8))) short bh8;    // 8 x bf16 (4 VGPRs)
typedef __attribute__((ext_vector_type(4))) float f32x4;  // MFMA 16x16 accumulator

#define NB 8
#define SLOTS 64
#define CAP 8192      // per-k pair capacity (expected ~4760, sigma ~68)
#define CROWS 49152   // compact h2c rows (expected ~35000)
#define PPB 16

// ---------------------------------------------------------------------------
// Layer 1: h1 = relu(subm_conv(feats, W1)) as bf16.
// ---------------------------------------------------------------------------
__global__ __launch_bounds__(256) void conv1_kernel(
    const float* __restrict__ feats, const float* __restrict__ W1,
    const int* __restrict__ nbr, __hip_bfloat16* __restrict__ h1b, int N) {
  __shared__ float W1s[27 * 256];
  __shared__ float fsT[27][16];
  __shared__ int s_nbr[PPB * 9];
  const int c = threadIdx.x;
  const int base = blockIdx.x * PPB;

  for (int t = c; t < 27 * 256; t += 256) W1s[t] = W1[t];
  if (c < PPB * 9) {
    int p = c / 9, k = c - p * 9;
    int gi = base + p;
    s_nbr[c] = (gi < N) ? nbr[gi * 9 + k] : -1;
  }
  __syncthreads();
  if (c < PPB * 9) {
    int p = c / 9, k = c - p * 9;
    int src = s_nbr[c];
    if (src >= 0) {
      fsT[k * 3 + 0][p] = feats[src * 3 + 0];
      fsT[k * 3 + 1][p] = feats[src * 3 + 1];
      fsT[k * 3 + 2][p] = feats[src * 3 + 2];
    } else {
      fsT[k * 3 + 0][p] = 0.f;
      fsT[k * 3 + 1][p] = 0.f;
      fsT[k * 3 + 2][p] = 0.f;
    }
  }
  __syncthreads();

  float acc[PPB];
#pragma unroll
  for (int p = 0; p < PPB; ++p) acc[p] = 0.f;

#pragma unroll 3
  for (int kj = 0; kj < 27; ++kj) {
    float w = W1s[kj * 256 + c];
    const float4* f4 = (const float4*)(&fsT[kj][0]);
    float4 fa = f4[0], fb = f4[1], fc = f4[2], fd = f4[3];
    acc[0]  += fa.x * w; acc[1]  += fa.y * w; acc[2]  += fa.z * w; acc[3]  += fa.w * w;
    acc[4]  += fb.x * w; acc[5]  += fb.y * w; acc[6]  += fb.z * w; acc[7]  += fb.w * w;
    acc[8]  += fc.x * w; acc[9]  += fc.y * w; acc[10] += fc.z * w; acc[11] += fc.w * w;
    acc[12] += fd.x * w; acc[13] += fd.y * w; acc[14] += fd.z * w; acc[15] += fd.w * w;
  }

#pragma unroll
  for (int p = 0; p < PPB; ++p) {
    int gi = base + p;
    if (gi < N) h1b[(long long)gi * 256 + c] = __float2bfloat16(fmaxf(acc[p], 0.f));
  }
}

// ---------------------------------------------------------------------------
// W2 fp32 [9][kk][n] -> bf16 transposed [9][n][kk].
// ---------------------------------------------------------------------------
__global__ __launch_bounds__(256) void w2t_kernel(
    const float* __restrict__ W2, __hip_bfloat16* __restrict__ w2bt) {
  __shared__ float tile[16][256];
  int k = blockIdx.x >> 4, t = blockIdx.x & 15;
  int tid = threadIdx.x;
#pragma unroll
  for (int r = 0; r < 16; ++r) tile[r][tid] = W2[k * 65536 + (t * 16 + r) * 256 + tid];
  __syncthreads();
#pragma unroll
  for (int r = 0; r < 16; ++r)
    w2bt[k * 65536 + tid * 256 + t * 16 + r] = __float2bfloat16(tile[r][tid]);
}

// ---------------------------------------------------------------------------
// Compaction with per-block aggregation (round-2 fix).
// ---------------------------------------------------------------------------
__global__ __launch_bounds__(256) void build_pairs_kernel(
    const int* __restrict__ nbr, const int* __restrict__ bid,
    int* __restrict__ nOff, int* __restrict__ cnt, float* __restrict__ bcnt,
    int* __restrict__ cidmap, int* __restrict__ psrc, int* __restrict__ pcid, int N) {
  __shared__ int l_cnt[10];
  __shared__ int l_base[10];
  __shared__ int l_bcnt[NB];
  const int tid = threadIdx.x;
  if (tid < 10) l_cnt[tid] = 0;
  if (tid < NB) l_bcnt[tid] = 0;
  __syncthreads();

  const int i = blockIdx.x * 256 + tid;
  const bool active = (i < N);
  int s[9];
  int kpos[9];
  int loc_cid = -1;
  if (active) {
#pragma unroll
    for (int k = 0; k < 9; ++k) s[k] = nbr[i * 9 + k];
    bool any = false;
#pragma unroll
    for (int k = 0; k < 9; ++k)
      if (k != 4 && s[k] >= 0) any = true;
    if (any) {
      loc_cid = atomicAdd(&l_cnt[9], 1);
#pragma unroll
      for (int k = 0; k < 9; ++k) {
        kpos[k] = -1;
        if (k != 4 && s[k] >= 0) kpos[k] = atomicAdd(&l_cnt[k], 1);
      }
    }
    atomicAdd(&l_bcnt[bid[i]], 1);
  }
  __syncthreads();

  if (tid < 9) l_base[tid] = (l_cnt[tid] > 0) ? atomicAdd(&cnt[tid], l_cnt[tid]) : 0;
  else if (tid == 9) l_base[9] = (l_cnt[9] > 0) ? atomicAdd(nOff, l_cnt[9]) : 0;
  if (tid >= 32 && tid < 32 + NB && l_bcnt[tid - 32] > 0)
    atomicAdd(&bcnt[tid - 32], (float)l_bcnt[tid - 32]);
  __syncthreads();

  if (active) {
    int cid = -1;
    if (loc_cid >= 0) {
      cid = l_base[9] + loc_cid;
      if (cid >= CROWS) cid = -1;
    }
    cidmap[i] = cid;
    if (cid >= 0) {
#pragma unroll
      for (int k = 0; k < 9; ++k) {
        if (k == 4 || kpos[k] < 0 || s[k] < 0) continue;
        int pos = l_base[k] + kpos[k];
        if (pos < CAP) {
          psrc[k * CAP + pos] = s[k];
          pcid[k * CAP + pos] = cid;
        }
      }
    }
  }
}

// ---------------------------------------------------------------------------
// Off-center taps: per (k, 16-row tile) gathered GEMM 16x256x256 bf16 MFMA,
// atomicAdd fp32 into compact h2c rows.
// ---------------------------------------------------------------------------
__global__ __launch_bounds__(256) void off_gemm_kernel(
    const __hip_bfloat16* __restrict__ h1, const __hip_bfloat16* __restrict__ w2bt,
    const int* __restrict__ cnt, const int* __restrict__ psrc,
    const int* __restrict__ pcid, float* __restrict__ h2c) {
  int koff = blockIdx.x >> 9;
  int tile = blockIdx.x & 511;
  int k = koff + (koff >= 4 ? 1 : 0);
  int cntk = cnt[k];
  if (tile * 16 >= cntk) return;

  __shared__ int s_src[16], s_cid[16];
  int tid = threadIdx.x;
  if (tid < 16) {
    int m = tile * 16 + tid;
    bool valid = m < cntk;
    s_src[tid] = valid ? psrc[k * CAP + m] : 0;
    s_cid[tid] = valid ? pcid[k * CAP + m] : -1;
  }
  __syncthreads();

  int wave = tid >> 6, lane = tid & 63, q = lane >> 4, m16 = lane & 15;
  const short* h1s = (const short*)h1;
  const short* wts = (const short*)w2bt + k * 65536;
  int srow = s_src[m16];

  // hoist the lane's full A slice (round-4: latency fix, same as center)
  bh8 aA[8];
#pragma unroll
  for (int ko = 0; ko < 8; ++ko)
    aA[ko] = *(const bh8*)(h1s + (long long)srow * 256 + ko * 32 + q * 8);

  f32x4 acc[4];
#pragma unroll
  for (int nj = 0; nj < 4; ++nj) acc[nj] = (f32x4)0.f;

#pragma unroll
  for (int ko = 0; ko < 8; ++ko) {
#pragma unroll
    for (int nj = 0; nj < 4; ++nj) {
      bh8 b = *(const bh8*)(wts + (wave * 64 + nj * 16 + m16) * 256 + ko * 32 + q * 8);
      acc[nj] = __builtin_amdgcn_mfma_f32_16x16x32_bf16(aA[ko], b, acc[nj], 0, 0, 0);
    }
  }
#pragma unroll
  for (int r = 0; r < 4; ++r) {
    int cid = s_cid[q * 4 + r];
    if (cid < 0) continue;
#pragma unroll
    for (int nj = 0; nj < 4; ++nj)
      atomicAdd(&h2c[(long long)cid * 256 + wave * 64 + nj * 16 + m16], acc[nj][r]);
  }
}

// ---------------------------------------------------------------------------
// Center tap dense GEMM h1 @ W2[4] fused with +h2c, ReLU, per-batch col sums.
// Round-4 rewrite: 64-row tiles, lane's full A slice (8 x bh8 = 128B) hoisted
// to registers before the MFMA loop -> 8 outstanding HBM loads, one latency
// exposure per block instead of 8 (was MfmaUtil 4.7%, latency-bound).
// ---------------------------------------------------------------------------
__global__ __launch_bounds__(256) void center_gemm_kernel(
    const __hip_bfloat16* __restrict__ h1, const __hip_bfloat16* __restrict__ w2bt,
    const float* __restrict__ h2c, const int* __restrict__ cidmap,
    const int* __restrict__ bid, float* __restrict__ psums, int N) {
  __shared__ float bsumS[2 * 128];
  int bx = blockIdx.x;
  int mt = bx >> 1;
  int nc = (bx & 1) << 7;   // column tile: 0 or 128
  int base = mt << 6;       // 64-row tile
  int tid = threadIdx.x;
  int wave = tid >> 6, lane = tid & 63;
  int q = lane >> 4, m16 = lane & 15;

  const short* h1s = (const short*)h1;
  const short* wts = (const short*)w2bt + 4 * 65536;

  int row = base + wave * 16 + m16;       // A row: m = lane&15
  int rowc = (row < N) ? row : (N - 1);

  bh8 aA[8];
#pragma unroll
  for (int ko = 0; ko < 8; ++ko)
    aA[ko] = *(const bh8*)(h1s + (long long)rowc * 256 + ko * 32 + q * 8);

  f32x4 acc[8];
#pragma unroll
  for (int nj = 0; nj < 8; ++nj) acc[nj] = (f32x4)0.f;

#pragma unroll
  for (int ko = 0; ko < 8; ++ko) {
    bh8 bfrag[8];
#pragma unroll
    for (int nj = 0; nj < 8; ++nj)
      bfrag[nj] = *(const bh8*)(wts + (nc + nj * 16 + m16) * 256 + ko * 32 + q * 8);
#pragma unroll
    for (int nj = 0; nj < 8; ++nj)
      acc[nj] = __builtin_amdgcn_mfma_f32_16x16x32_bf16(aA[ko], bfrag[nj], acc[nj], 0, 0, 0);
  }

  // ---- fused epilogue ----
  bsumS[tid] = 0.f;
  __syncthreads();

  int b0 = bid[base];
  int blast = bid[(base + 63 < N) ? base + 63 : N - 1];

  float sacc[2][8];
#pragma unroll
  for (int lb = 0; lb < 2; ++lb)
#pragma unroll
    for (int nj = 0; nj < 8; ++nj) sacc[lb][nj] = 0.f;

#pragma unroll
  for (int r = 0; r < 4; ++r) {
    int rw = base + wave * 16 + q * 4 + r;  // C/D row
    if (rw >= N) continue;
    int cid = cidmap[rw];
    int lb = (bid[rw] != b0) ? 1 : 0;
#pragma unroll
    for (int nj = 0; nj < 8; ++nj) {
      float v = acc[nj][r];
      if (cid >= 0) v += h2c[(long long)cid * 256 + nc + nj * 16 + m16];
      v = fmaxf(v, 0.f);
      sacc[lb][nj] += v;
    }
  }
#pragma unroll
  for (int lb = 0; lb < 2; ++lb)
#pragma unroll
    for (int nj = 0; nj < 8; ++nj) {
      float v = sacc[lb][nj];
      v += __shfl_xor(v, 16, 64);
      v += __shfl_xor(v, 32, 64);
      if (q == 0) atomicAdd(&bsumS[lb * 128 + nj * 16 + m16], v);
    }
  __syncthreads();

  int slot = bx & (SLOTS - 1);
  {
    int lb = tid >> 7, coll = tid & 127;
    int b = b0 + lb;
    bool do2 = (blast != b0);
    if ((lb == 0 || do2) && b < NB) {
      atomicAdd(&psums[(slot * NB + b) * 256 + nc + coll], bsumS[tid]);
    }
  }
}

__global__ void finalize_kernel(const float* __restrict__ psums,
                                const float* __restrict__ bcnt,
                                float* __restrict__ out) {
  int b = blockIdx.x, c = threadIdx.x;
  float s = 0.f;
  for (int t = 0; t < SLOTS; ++t) s += psums[(t * NB + b) * 256 + c];
  out[b * 256 + c] = s / bcnt[b];
}

extern "C" void kernel_launch(void* const* d_in, const int* in_sizes, int n_in,
                              void* d_out, int out_size, void* d_ws, size_t ws_size,
                              hipStream_t stream) {
  const float* feats = (const float*)d_in[0];
  const float* W1    = (const float*)d_in[1];
  const float* W2    = (const float*)d_in[2];
  const int*   nbr   = (const int*)d_in[3];
  const int*   bid   = (const int*)d_in[4];
  float* out = (float*)d_out;
  const int N = in_sizes[0] / 3;

  // ---- workspace layout (256B-aligned segments) ----
  char* ws = (char*)d_ws;
  size_t o = 0;
  float* psums = (float*)(ws + o); o += (size_t)SLOTS * NB * 256 * 4;
  float* bcnt  = (float*)(ws + o); o += NB * 4;
  int*   nOff  = (int*)(ws + o);   o += 4;
  int*   cnt   = (int*)(ws + o);   o += 9 * 4;
  o = (o + 255) & ~(size_t)255;
  size_t zero1 = o;                         // memset [0, zero1)
  int* psrc = (int*)(ws + o); o += (size_t)9 * CAP * 4;
  int* pcid = (int*)(ws + o); o += (size_t)9 * CAP * 4;
  int* cidmap = (int*)(ws + o); o += (size_t)N * 4;
  o = (o + 255) & ~(size_t)255;
  float* h2c = (float*)(ws + o); o += (size_t)CROWS * 256 * 4;
  __hip_bfloat16* w2bt = (__hip_bfloat16*)(ws + o); o += (size_t)9 * 65536 * 2;
  __hip_bfloat16* h1b  = (__hip_bfloat16*)(ws + o); o += (size_t)N * 256 * 2;

  hipMemsetAsync(d_ws, 0, zero1, stream);
  hipMemsetAsync(h2c, 0, (size_t)CROWS * 256 * 4, stream);

  conv1_kernel<<<(N + PPB - 1) / PPB, 256, 0, stream>>>(feats, W1, nbr, h1b, N);
  w2t_kernel<<<9 * 16, 256, 0, stream>>>(W2, w2bt);
  build_pairs_kernel<<<(N + 255) / 256, 256, 0, stream>>>(nbr, bid, nOff, cnt, bcnt,
                                                          cidmap, psrc, pcid, N);
  off_gemm_kernel<<<8 * 512, 256, 0, stream>>>(h1b, w2bt, cnt, psrc, pcid, h2c);
  center_gemm_kernel<<<((N + 63) / 64) * 2, 256, 0, stream>>>(h1b, w2bt, h2c,
                                                              cidmap, bid, psums, N);
  finalize_kernel<<<NB, 256, 0, stream>>>(psums, bcnt, out);
}

// Round 5
// 363.869 us; speedup vs baseline: 1.4085x; 1.4085x over previous
//
#include <hip/hip_runtime.h>
#include <hip/hip_bf16.h>

typedef __attribute__((ext_vector_type(8))) short bh8;    // 8 x bf16 (4 VGPRs)
typedef __attribute__((ext_vector_type(4))) float f32x4;  // MFMA 16x16 accumulator

#define NB 8
#define SLOTS 64
#define CAP 8192      // per-k pair capacity (expected ~4760, sigma ~68)
#define CROWS 49152   // compact h2c rows (expected ~35000)
#define PPB 16

// ---------------------------------------------------------------------------
// Layer 1: h1 = relu(subm_conv(feats, W1)) as bf16.
// ---------------------------------------------------------------------------
__global__ __launch_bounds__(256) void conv1_kernel(
    const float* __restrict__ feats, const float* __restrict__ W1,
    const int* __restrict__ nbr, __hip_bfloat16* __restrict__ h1b, int N) {
  __shared__ float W1s[27 * 256];
  __shared__ float fsT[27][16];
  __shared__ int s_nbr[PPB * 9];
  const int c = threadIdx.x;
  const int base = blockIdx.x * PPB;

  for (int t = c; t < 27 * 256; t += 256) W1s[t] = W1[t];
  if (c < PPB * 9) {
    int p = c / 9, k = c - p * 9;
    int gi = base + p;
    s_nbr[c] = (gi < N) ? nbr[gi * 9 + k] : -1;
  }
  __syncthreads();
  if (c < PPB * 9) {
    int p = c / 9, k = c - p * 9;
    int src = s_nbr[c];
    if (src >= 0) {
      fsT[k * 3 + 0][p] = feats[src * 3 + 0];
      fsT[k * 3 + 1][p] = feats[src * 3 + 1];
      fsT[k * 3 + 2][p] = feats[src * 3 + 2];
    } else {
      fsT[k * 3 + 0][p] = 0.f;
      fsT[k * 3 + 1][p] = 0.f;
      fsT[k * 3 + 2][p] = 0.f;
    }
  }
  __syncthreads();

  float acc[PPB];
#pragma unroll
  for (int p = 0; p < PPB; ++p) acc[p] = 0.f;

#pragma unroll 3
  for (int kj = 0; kj < 27; ++kj) {
    float w = W1s[kj * 256 + c];
    const float4* f4 = (const float4*)(&fsT[kj][0]);
    float4 fa = f4[0], fb = f4[1], fc = f4[2], fd = f4[3];
    acc[0]  += fa.x * w; acc[1]  += fa.y * w; acc[2]  += fa.z * w; acc[3]  += fa.w * w;
    acc[4]  += fb.x * w; acc[5]  += fb.y * w; acc[6]  += fb.z * w; acc[7]  += fb.w * w;
    acc[8]  += fc.x * w; acc[9]  += fc.y * w; acc[10] += fc.z * w; acc[11] += fc.w * w;
    acc[12] += fd.x * w; acc[13] += fd.y * w; acc[14] += fd.z * w; acc[15] += fd.w * w;
  }

#pragma unroll
  for (int p = 0; p < PPB; ++p) {
    int gi = base + p;
    if (gi < N) h1b[(long long)gi * 256 + c] = __float2bfloat16(fmaxf(acc[p], 0.f));
  }
}

// ---------------------------------------------------------------------------
// W2 fp32 [9][kk][n] -> bf16 transposed [9][n][kk].
// ---------------------------------------------------------------------------
__global__ __launch_bounds__(256) void w2t_kernel(
    const float* __restrict__ W2, __hip_bfloat16* __restrict__ w2bt) {
  __shared__ float tile[16][256];
  int k = blockIdx.x >> 4, t = blockIdx.x & 15;
  int tid = threadIdx.x;
#pragma unroll
  for (int r = 0; r < 16; ++r) tile[r][tid] = W2[k * 65536 + (t * 16 + r) * 256 + tid];
  __syncthreads();
#pragma unroll
  for (int r = 0; r < 16; ++r)
    w2bt[k * 65536 + tid * 256 + t * 16 + r] = __float2bfloat16(tile[r][tid]);
}

// ---------------------------------------------------------------------------
// Compaction with per-block aggregation (round-2 fix).
// ---------------------------------------------------------------------------
__global__ __launch_bounds__(256) void build_pairs_kernel(
    const int* __restrict__ nbr, const int* __restrict__ bid,
    int* __restrict__ nOff, int* __restrict__ cnt, float* __restrict__ bcnt,
    int* __restrict__ cidmap, int* __restrict__ psrc, int* __restrict__ pcid, int N) {
  __shared__ int l_cnt[10];
  __shared__ int l_base[10];
  __shared__ int l_bcnt[NB];
  const int tid = threadIdx.x;
  if (tid < 10) l_cnt[tid] = 0;
  if (tid < NB) l_bcnt[tid] = 0;
  __syncthreads();

  const int i = blockIdx.x * 256 + tid;
  const bool active = (i < N);
  int s[9];
  int kpos[9];
  int loc_cid = -1;
  if (active) {
#pragma unroll
    for (int k = 0; k < 9; ++k) s[k] = nbr[i * 9 + k];
    bool any = false;
#pragma unroll
    for (int k = 0; k < 9; ++k)
      if (k != 4 && s[k] >= 0) any = true;
    if (any) {
      loc_cid = atomicAdd(&l_cnt[9], 1);
#pragma unroll
      for (int k = 0; k < 9; ++k) {
        kpos[k] = -1;
        if (k != 4 && s[k] >= 0) kpos[k] = atomicAdd(&l_cnt[k], 1);
      }
    }
    atomicAdd(&l_bcnt[bid[i]], 1);
  }
  __syncthreads();

  if (tid < 9) l_base[tid] = (l_cnt[tid] > 0) ? atomicAdd(&cnt[tid], l_cnt[tid]) : 0;
  else if (tid == 9) l_base[9] = (l_cnt[9] > 0) ? atomicAdd(nOff, l_cnt[9]) : 0;
  if (tid >= 32 && tid < 32 + NB && l_bcnt[tid - 32] > 0)
    atomicAdd(&bcnt[tid - 32], (float)l_bcnt[tid - 32]);
  __syncthreads();

  if (active) {
    int cid = -1;
    if (loc_cid >= 0) {
      cid = l_base[9] + loc_cid;
      if (cid >= CROWS) cid = -1;
    }
    cidmap[i] = cid;
    if (cid >= 0) {
#pragma unroll
      for (int k = 0; k < 9; ++k) {
        if (k == 4 || kpos[k] < 0 || s[k] < 0) continue;
        int pos = l_base[k] + kpos[k];
        if (pos < CAP) {
          psrc[k * CAP + pos] = s[k];
          pcid[k * CAP + pos] = cid;
        }
      }
    }
  }
}

// ---------------------------------------------------------------------------
// Off-center taps: per (k, 16-row tile) gathered GEMM 16x256x256 bf16 MFMA,
// atomicAdd fp32 into compact h2c rows.
// ---------------------------------------------------------------------------
__global__ __launch_bounds__(256) void off_gemm_kernel(
    const __hip_bfloat16* __restrict__ h1, const __hip_bfloat16* __restrict__ w2bt,
    const int* __restrict__ cnt, const int* __restrict__ psrc,
    const int* __restrict__ pcid, float* __restrict__ h2c) {
  int koff = blockIdx.x >> 9;
  int tile = blockIdx.x & 511;
  int k = koff + (koff >= 4 ? 1 : 0);
  int cntk = cnt[k];
  if (tile * 16 >= cntk) return;

  __shared__ int s_src[16], s_cid[16];
  int tid = threadIdx.x;
  if (tid < 16) {
    int m = tile * 16 + tid;
    bool valid = m < cntk;
    s_src[tid] = valid ? psrc[k * CAP + m] : 0;
    s_cid[tid] = valid ? pcid[k * CAP + m] : -1;
  }
  __syncthreads();

  int wave = tid >> 6, lane = tid & 63, q = lane >> 4, m16 = lane & 15;
  const short* h1s = (const short*)h1;
  const short* wts = (const short*)w2bt + k * 65536;
  int srow = s_src[m16];

  bh8 aA[8];
#pragma unroll
  for (int ko = 0; ko < 8; ++ko)
    aA[ko] = *(const bh8*)(h1s + (long long)srow * 256 + ko * 32 + q * 8);

  f32x4 acc[4];
#pragma unroll
  for (int nj = 0; nj < 4; ++nj) acc[nj] = (f32x4)0.f;

#pragma unroll
  for (int ko = 0; ko < 8; ++ko) {
#pragma unroll
    for (int nj = 0; nj < 4; ++nj) {
      bh8 b = *(const bh8*)(wts + (wave * 64 + nj * 16 + m16) * 256 + ko * 32 + q * 8);
      acc[nj] = __builtin_amdgcn_mfma_f32_16x16x32_bf16(aA[ko], b, acc[nj], 0, 0, 0);
    }
  }
#pragma unroll
  for (int r = 0; r < 4; ++r) {
    int cid = s_cid[q * 4 + r];
    if (cid < 0) continue;
#pragma unroll
    for (int nj = 0; nj < 4; ++nj)
      atomicAdd(&h2c[(long long)cid * 256 + wave * 64 + nj * 16 + m16], acc[nj][r]);
  }
}

// ---------------------------------------------------------------------------
// Center tap dense GEMM h1 @ W2[4] fused with +h2c, ReLU, per-batch col sums.
// Round-5 rewrite (m97-style): 512 thr / 8 waves, 256 rows x 256 cols per
// block. B (128 KB) staged in LDS ONCE with +n chunk-rotation skew (2-way
// bank access = free). Wave = 64 rows x 128 cols: acc[4][8] -> 4 MFMA per
// B ds_read_b128, 8 per A global load. A double-buffered in registers.
// Round 4 failed because 1 MFMA/B-load made it cache-issue bound.
// ---------------------------------------------------------------------------
__global__ __launch_bounds__(512, 2) void center_gemm_kernel(
    const __hip_bfloat16* __restrict__ h1, const __hip_bfloat16* __restrict__ w2bt,
    const float* __restrict__ h2c, const int* __restrict__ cidmap,
    const int* __restrict__ bid, float* __restrict__ psums, int N) {
  __shared__ __align__(16) short Bs[256 * 256];  // 128 KB, skewed
  __shared__ float bsumS[512];
  __shared__ int s_bid[256], s_cid[256];

  const int tid = threadIdx.x;
  const int bx = blockIdx.x;
  const int base = bx << 8;            // 256 rows per block
  const int wave = tid >> 6, lane = tid & 63;
  const int q = lane >> 4, m16 = lane & 15;
  const int wrow = (wave & 3) << 6;    // wave row offset: 0/64/128/192
  const int wcol = (wave >> 2) << 7;   // wave col half: 0/128

  const short* h1s = (const short*)h1;
  const short* wts = (const short*)w2bt + 4 * 65536;  // center tap, [n][kk]

  // stage bid/cid for the block's rows
  if (tid < 256) {
    int gi = base + tid;
    s_bid[tid] = (gi < N) ? bid[gi] : -1;
    s_cid[tid] = (gi < N) ? cidmap[gi] : -1;
  }
  bsumS[tid] = 0.f;

  // stage B into LDS with skew: chunk m (16B) of row n stored at pos (m+n)&31
  {
    const int n0 = tid >> 5, p = tid & 31;
    int4* BsV = (int4*)Bs;
#pragma unroll
    for (int pass = 0; pass < 16; ++pass) {
      int n = pass * 16 + n0;
      int m = (p - n) & 31;
      int4 v = *(const int4*)(wts + n * 256 + m * 8);
      BsV[pass * 512 + tid] = v;  // dest pos = n*32 + (m+n)&31 = n*32 + p
    }
  }
  __syncthreads();

  // A rows for this wave (m = lane&15 per MFMA A-layout)
  const short* aptr[4];
#pragma unroll
  for (int mi = 0; mi < 4; ++mi) {
    int r = base + wrow + mi * 16 + m16;
    int rc = (r < N) ? r : (N - 1);
    aptr[mi] = h1s + (long long)rc * 256 + q * 8;
  }

  // B fragment LDS offsets: row n = wcol + nj*16 + m16, skewed chunk
  int nB[8], pq[8];
#pragma unroll
  for (int nj = 0; nj < 8; ++nj) {
    nB[nj] = wcol + nj * 16 + m16;
    pq[nj] = (q + nB[nj]) & 31;
  }

  f32x4 acc[4][8];
#pragma unroll
  for (int mi = 0; mi < 4; ++mi)
#pragma unroll
    for (int nj = 0; nj < 8; ++nj) acc[mi][nj] = (f32x4)0.f;

  bh8 aA[2][4];
#pragma unroll
  for (int mi = 0; mi < 4; ++mi) aA[0][mi] = *(const bh8*)(aptr[mi]);

#pragma unroll
  for (int ko = 0; ko < 8; ++ko) {
    const int cur = ko & 1;
    if (ko < 7) {
#pragma unroll
      for (int mi = 0; mi < 4; ++mi)
        aA[cur ^ 1][mi] = *(const bh8*)(aptr[mi] + (ko + 1) * 32);
    }
    bh8 bfr[8];
#pragma unroll
    for (int nj = 0; nj < 8; ++nj)
      bfr[nj] = *(const bh8*)(Bs + nB[nj] * 256 + ((ko * 4 + pq[nj]) & 31) * 8);
#pragma unroll
    for (int mi = 0; mi < 4; ++mi)
#pragma unroll
      for (int nj = 0; nj < 8; ++nj)
        acc[mi][nj] = __builtin_amdgcn_mfma_f32_16x16x32_bf16(aA[cur][mi], bfr[nj], acc[mi][nj], 0, 0, 0);
  }

  // ---- fused epilogue: + h2c, ReLU, per-batch column sums ----
  __syncthreads();  // bsumS zero + staging done (already sync'd); keeps ordering

  const int b0 = s_bid[0];
  const int lastloc = (base + 255 < N) ? 255 : (N - 1 - base);
  const int blast = s_bid[lastloc];

  float sacc[2][8];
#pragma unroll
  for (int lb = 0; lb < 2; ++lb)
#pragma unroll
    for (int nj = 0; nj < 8; ++nj) sacc[lb][nj] = 0.f;

#pragma unroll
  for (int mi = 0; mi < 4; ++mi) {
#pragma unroll
    for (int rr = 0; rr < 4; ++rr) {
      int lrow = wrow + mi * 16 + q * 4 + rr;   // C/D row = q*4+reg
      if (base + lrow >= N) continue;
      int cid = s_cid[lrow];
      int lb = (s_bid[lrow] != b0) ? 1 : 0;
#pragma unroll
      for (int nj = 0; nj < 8; ++nj) {
        float v = acc[mi][nj][rr];
        if (cid >= 0) v += h2c[(long long)cid * 256 + wcol + nj * 16 + m16];
        v = fmaxf(v, 0.f);
        sacc[lb][nj] += v;
      }
    }
  }
#pragma unroll
  for (int lb = 0; lb < 2; ++lb)
#pragma unroll
    for (int nj = 0; nj < 8; ++nj) {
      float v = sacc[lb][nj];
      v += __shfl_xor(v, 16, 64);
      v += __shfl_xor(v, 32, 64);
      if (q == 0) atomicAdd(&bsumS[lb * 256 + wcol + nj * 16 + m16], v);
    }
  __syncthreads();

  {
    int slot = bx & (SLOTS - 1);
    int lb = tid >> 8, coll = tid & 255;
    int b = b0 + lb;
    bool do2 = (blast != b0);
    if ((lb == 0 || do2) && b >= 0 && b < NB) {
      atomicAdd(&psums[(slot * NB + b) * 256 + coll], bsumS[tid]);
    }
  }
}

__global__ void finalize_kernel(const float* __restrict__ psums,
                                const float* __restrict__ bcnt,
                                float* __restrict__ out) {
  int b = blockIdx.x, c = threadIdx.x;
  float s = 0.f;
  for (int t = 0; t < SLOTS; ++t) s += psums[(t * NB + b) * 256 + c];
  out[b * 256 + c] = s / bcnt[b];
}

extern "C" void kernel_launch(void* const* d_in, const int* in_sizes, int n_in,
                              void* d_out, int out_size, void* d_ws, size_t ws_size,
                              hipStream_t stream) {
  const float* feats = (const float*)d_in[0];
  const float* W1    = (const float*)d_in[1];
  const float* W2    = (const float*)d_in[2];
  const int*   nbr   = (const int*)d_in[3];
  const int*   bid   = (const int*)d_in[4];
  float* out = (float*)d_out;
  const int N = in_sizes[0] / 3;

  // ---- workspace layout (256B-aligned segments) ----
  char* ws = (char*)d_ws;
  size_t o = 0;
  float* psums = (float*)(ws + o); o += (size_t)SLOTS * NB * 256 * 4;
  float* bcnt  = (float*)(ws + o); o += NB * 4;
  int*   nOff  = (int*)(ws + o);   o += 4;
  int*   cnt   = (int*)(ws + o);   o += 9 * 4;
  o = (o + 255) & ~(size_t)255;
  size_t zero1 = o;                         // memset [0, zero1)
  int* psrc = (int*)(ws + o); o += (size_t)9 * CAP * 4;
  int* pcid = (int*)(ws + o); o += (size_t)9 * CAP * 4;
  int* cidmap = (int*)(ws + o); o += (size_t)N * 4;
  o = (o + 255) & ~(size_t)255;
  float* h2c = (float*)(ws + o); o += (size_t)CROWS * 256 * 4;
  __hip_bfloat16* w2bt = (__hip_bfloat16*)(ws + o); o += (size_t)9 * 65536 * 2;
  __hip_bfloat16* h1b  = (__hip_bfloat16*)(ws + o); o += (size_t)N * 256 * 2;

  hipMemsetAsync(d_ws, 0, zero1, stream);
  hipMemsetAsync(h2c, 0, (size_t)CROWS * 256 * 4, stream);

  conv1_kernel<<<(N + PPB - 1) / PPB, 256, 0, stream>>>(feats, W1, nbr, h1b, N);
  w2t_kernel<<<9 * 16, 256, 0, stream>>>(W2, w2bt);
  build_pairs_kernel<<<(N + 255) / 256, 256, 0, stream>>>(nbr, bid, nOff, cnt, bcnt,
                                                          cidmap, psrc, pcid, N);
  off_gemm_kernel<<<8 * 512, 256, 0, stream>>>(h1b, w2bt, cnt, psrc, pcid, h2c);
  center_gemm_kernel<<<(N + 255) / 256, 512, 0, stream>>>(h1b, w2bt, h2c,
                                                          cidmap, bid, psums, N);
  finalize_kernel<<<NB, 256, 0, stream>>>(psums, bcnt, out);
}